// Round 24
// baseline (167.539 us; speedup 1.0000x reference)
//
#include <hip/hip_runtime.h>
#include <hip/hip_bf16.h>
#include <math.h>

typedef unsigned short u16;
typedef short s16x8 __attribute__((ext_vector_type(8)));
typedef u16 u16x4 __attribute__((ext_vector_type(4)));
typedef __bf16 bf16x8_t __attribute__((ext_vector_type(8)));
typedef float f32x4 __attribute__((ext_vector_type(4)));

#define DEVI static __device__ __forceinline__

static constexpr int Bn = 2, Tn = 2048, Cn = 2048, Hn = 32, HKVn = 8, Dn = 64;
static constexpr int NCOL = Cn + 2 * HKVn * Dn;   // 3072
// Q pre-scale: 1/sqrt(64) * log2(e) -> scores already in exp2 domain
#define QSCALE 0.18033688011f
// Fixed softmax max (exp2 domain): scores ~N(0,1.44), max over 4M ~ +-8;
// M=24 is ~16 sigma; p = exp2(s-24) keeps full relative precision.
#define FMAXC 24.0f

#if __has_builtin(__builtin_amdgcn_exp2f)
#define EXP2(x) __builtin_amdgcn_exp2f(x)
#else
#define EXP2(x) exp2f(x)
#endif

DEVI u16 f2b(float f) {
  __hip_bfloat16 h = __float2bfloat16(f);
  return __builtin_bit_cast(u16, h);
}
DEVI float b2f(u16 u) {
  __hip_bfloat16 h = __builtin_bit_cast(__hip_bfloat16, u);
  return __bfloat162float(h);
}
DEVI bf16x8_t ld8(const u16* p) {
  s16x8 v = *reinterpret_cast<const s16x8*>(p);
  return __builtin_bit_cast(bf16x8_t, v);
}
DEVI f32x4 mfma16(bf16x8_t a, bf16x8_t b, f32x4 c) {
  return __builtin_amdgcn_mfma_f32_16x16x32_bf16(a, b, c, 0, 0, 0);
}
DEVI void async16(u16* lds_dst, const u16* gsrc) {
  __builtin_amdgcn_global_load_lds(
      (__attribute__((address_space(1))) void*)(gsrc),
      (__attribute__((address_space(3))) void*)(lds_dst), 16, 0, 0);
}

// ---------------- fused input casts + rope table (1 launch) ----------------
__global__ void cast_all(const float* __restrict__ x, const float* __restrict__ wq,
                         const float* __restrict__ wk, const float* __restrict__ wv,
                         const float* __restrict__ wc, u16* __restrict__ xb,
                         u16* __restrict__ wqkvb, u16* __restrict__ wcb,
                         float* __restrict__ cs, float* __restrict__ sn) {
  constexpr int NX4 = 2097152, NWQ4 = 1048576, NWK4 = 262144;
  constexpr int TOT = NX4 + NWQ4 + 2 * NWK4 + NWQ4;   // 4718592
  const int stride = gridDim.x * blockDim.x;
  const int tid0 = blockIdx.x * blockDim.x + threadIdx.x;
  for (int i = tid0; i < TOT; i += stride) {
    const float4* sv;
    u16x4* dv;
    if (i < NX4) {
      sv = (const float4*)x + i; dv = (u16x4*)xb + i;
    } else if (i < NX4 + NWQ4) {
      const int j = i - NX4;
      sv = (const float4*)wq + j; dv = (u16x4*)wqkvb + j;
    } else if (i < NX4 + NWQ4 + NWK4) {
      const int j = i - NX4 - NWQ4;
      sv = (const float4*)wk + j; dv = (u16x4*)wqkvb + NWQ4 + j;
    } else if (i < NX4 + NWQ4 + 2 * NWK4) {
      const int j = i - NX4 - NWQ4 - NWK4;
      sv = (const float4*)wv + j; dv = (u16x4*)wqkvb + NWQ4 + NWK4 + j;
    } else {
      const int j = i - NX4 - NWQ4 - 2 * NWK4;
      sv = (const float4*)wc + j; dv = (u16x4*)wcb + j;
    }
    const float4 v = *sv;
    u16x4 o = { f2b(v.x), f2b(v.y), f2b(v.z), f2b(v.w) };
    *dv = o;
  }
  // rope table: 2048 x 32 entries
  if (tid0 < Tn * 32) {
    const int t = tid0 >> 5, d2 = tid0 & 31;
    const float inv = powf(10000.0f, -(float)d2 / 32.0f);
    const float fr = (float)t * inv;
    cs[tid0] = cosf(fr);
    sn[tid0] = sinf(fr);
  }
}

// ======== QKV GEMM, 128x128 tile, BK=32, 8 waves, counted-vmcnt pipeline =====
// R24: occupancy rung 2 -> 4 blocks/CU (the R22 lever, next step). LDS/buf =
// (128+128)x32x2B = 16KB, dbuf 32KB -> 4 blocks x 8 waves = 32 waves/CU (max).
// BN=128: 2048/2560 are tile-aligned -> every tile region-pure (no mixed
// branches). Stage: 1 async16/thread per matrix, steady-state vmcnt(2).
// 64B LDS rows: conflict-free chunk swizzle chunk^=(row>>1)&3 (R10-derived,
// measured 0 conflicts); stage source pre-swizzle (tid&3)^((tid>>3)&3).
__global__ __launch_bounds__(512, 2)
void gemm_qkv_rope256(const u16* __restrict__ A, const u16* __restrict__ Bm,
                      const float* __restrict__ cs, const float* __restrict__ sn,
                      u16* __restrict__ qo, u16* __restrict__ ko,
                      u16* __restrict__ vo, int K) {
  __shared__ u16 lds[2][8192];   // 32 KB total: A 128x32 | B 128x32
  const int tid = threadIdx.x;
  const int mb = blockIdx.x * 128, nb = blockIdx.y * 128;
  const int lane = tid & 63, lr = lane & 15, lg = lane >> 4;
  const int w = tid >> 6, wm = w >> 2, wn = w & 3;
  const int nk = K >> 5;   // BK = 32 -> 64 tiles

  const int srow = tid >> 2;                       // 0..127
  const int scol = ((tid & 3) ^ ((tid >> 3) & 3)); // pre-swizzled source chunk
  const u16* asrc = A + (size_t)(mb + srow) * K + scol * 8;
  const u16* bsrc = Bm + (size_t)(nb + srow) * K + scol * 8;

  auto stage = [&](int buf, int kt) {
    async16(&lds[buf][tid * 8], asrc + kt * 32);
    async16(&lds[buf][4096 + tid * 8], bsrc + kt * 32);
  };

  f32x4 acc[4][2] = {};
  stage(0, 0);
  stage(1, 1);

  const int rsw = (lr >> 1) & 3;
  for (int kt = 0; kt < nk; ++kt) {
    if (kt + 1 < nk) asm volatile("s_waitcnt vmcnt(2)" ::: "memory");
    else             asm volatile("s_waitcnt vmcnt(0)" ::: "memory");
    asm volatile("s_barrier" ::: "memory");
    const u16* base = lds[kt & 1];
    bf16x8_t bfr[2];
#pragma unroll
    for (int n = 0; n < 2; ++n)
      bfr[n] = ld8(base + 4096 + (wn * 32 + n * 16 + lr) * 32 +
                   ((lg ^ rsw) * 8));
    bf16x8_t af[4];
#pragma unroll
    for (int m = 0; m < 4; ++m)
      af[m] = ld8(base + (wm * 64 + m * 16 + lr) * 32 + ((lg ^ rsw) * 8));
    __builtin_amdgcn_s_setprio(1);
#pragma unroll
    for (int m = 0; m < 4; ++m)
#pragma unroll
      for (int n = 0; n < 2; ++n)
        acc[m][n] = mfma16(af[m], bfr[n], acc[m][n]);
    __builtin_amdgcn_s_setprio(0);
    asm volatile("s_barrier" ::: "memory");   // all waves done reading buf
    if (kt + 2 < nk) stage(kt & 1, kt + 2);
  }
  __syncthreads();

  if (nb >= Cn + 512) {
    // ---- pure-V tile: direct packed stores (r-quad = 4 consecutive t) ----
#pragma unroll
    for (int m = 0; m < 4; ++m)
#pragma unroll
      for (int n = 0; n < 2; ++n) {
        const int col = nb + wn * 32 + n * 16 + lr;
        const int cc = col - Cn - 512;
        const int d = cc & 63, h = cc >> 6;
        const int row0 = mb + wm * 64 + m * 16 + lg * 4;
        const int b = row0 >> 11, t0 = row0 & 2047;
        u16x4 pk = { f2b(acc[m][n][0]), f2b(acc[m][n][1]),
                     f2b(acc[m][n][2]), f2b(acc[m][n][3]) };
        *reinterpret_cast<u16x4*>(
            vo + (((size_t)b * HKVn + h) * Dn + d) * Tn + t0) = pk;
      }
    return;
  }

  // ---- pure Q or K tile: acc -> 128x128 LDS tile -> RoPE re-read ----
  u16* tile = &lds[0][0];     // 16384 u16 = 32KB (whole array)
#pragma unroll
  for (int m = 0; m < 4; ++m)
#pragma unroll
    for (int n = 0; n < 2; ++n) {
      const int colc = wn * 32 + n * 16 + lr;    // 0..127
#pragma unroll
      for (int r = 0; r < 4; ++r) {
        const int row = wm * 64 + m * 16 + lg * 4 + r;
        tile[row * 128 + (((colc >> 3) ^ (row & 15)) << 3) + (colc & 7)] =
            f2b(acc[m][n][r]);
      }
    }
  __syncthreads();

  const bool isQ = (nb < Cn);
  // 128 rows x 16 chunks = 2048 units
#pragma unroll
  for (int it = 0; it < 4; ++it) {
    const int unit = it * 512 + tid;
    const int tl = unit >> 4;              // tile row 0..127
    const int ch = unit & 15;              // chunk 0..15
    const int head = ch >> 3;              // 0..1 heads per 128-col tile
    const int c = ch & 7;                  // chunk within 64-col head
    const int sw = tl & 15;
    const s16x8 v0 = *reinterpret_cast<const s16x8*>(
        tile + tl * 128 + ((ch ^ sw) << 3));
    const s16x8 v1 = *reinterpret_cast<const s16x8*>(
        tile + tl * 128 + (((ch ^ 4) ^ sw) << 3));
    const int grow = mb + tl, b = grow >> 11, t = grow & 2047;
    const float4 c0 = *reinterpret_cast<const float4*>(cs + t * 32 + (c & 3) * 8);
    const float4 c1 = *reinterpret_cast<const float4*>(cs + t * 32 + (c & 3) * 8 + 4);
    const float4 s0 = *reinterpret_cast<const float4*>(sn + t * 32 + (c & 3) * 8);
    const float4 s1 = *reinterpret_cast<const float4*>(sn + t * 32 + (c & 3) * 8 + 4);
    const float cf[8] = { c0.x, c0.y, c0.z, c0.w, c1.x, c1.y, c1.z, c1.w };
    const float sf[8] = { s0.x, s0.y, s0.z, s0.w, s1.x, s1.y, s1.z, s1.w };
    const float sgn = (c < 4) ? -1.f : 1.f;
    const float scale = isQ ? QSCALE : 1.f;
    u16 outv[8];
#pragma unroll
    for (int e = 0; e < 8; ++e) {
      const float a0 = b2f((u16)v0[e]);
      const float a1 = b2f((u16)v1[e]);
      outv[e] = f2b((a0 * cf[e] + sgn * a1 * sf[e]) * scale);
    }
    u16* dst;
    if (isQ) {
      const int h = (nb >> 6) + head;
      dst = qo + (((size_t)b * Hn + h) * Tn + t) * Dn + c * 8;
    } else {
      const int h = ((nb - Cn) >> 6) + head;
      dst = ko + (((size_t)b * HKVn + h) * Tn + t) * Dn + c * 8;
    }
    *reinterpret_cast<s16x8*>(dst) = *reinterpret_cast<const s16x8*>(outv);
  }
}

// ======== proj GEMM, 128x128 tile, BK=64, 8 waves, counted-vmcnt pipeline ====
__global__ __launch_bounds__(512, 2)
void gemm_proj256(const u16* __restrict__ A, const u16* __restrict__ Bm,
                  float* __restrict__ Cm, int N, int K) {
  __shared__ u16 lds[2][16384];   // 64 KB
  const int tid = threadIdx.x;
  const int mb = blockIdx.x * 128, nb = blockIdx.y * 128;
  const int lane = tid & 63, lr = lane & 15, lg = lane >> 4;
  const int w = tid >> 6, wm = w >> 2, wn = w & 3;
  const int nk = K >> 6;   // BK = 64

  auto stage = [&](int buf, int kt) {
#pragma unroll
    for (int h = 0; h < 4; ++h) {
      if (h < 2) {
        const int s = h * 512 + tid;          // A slots 0..1023
        const int row = s >> 3;               // 0..127
        const int c = (s & 7) ^ (row & 7);
        async16(&lds[buf][s * 8], A + (size_t)(mb + row) * K + kt * 64 + c * 8);
      } else {
        const int s = (h - 2) * 512 + tid;    // B slots 0..1023
        const int row = s >> 3;               // 0..127
        const int c = (s & 7) ^ (row & 7);
        async16(&lds[buf][8192 + s * 8],
                Bm + (size_t)(nb + row) * K + kt * 64 + c * 8);
      }
    }
  };

  f32x4 acc[4][2] = {};
  stage(0, 0);
  stage(1, 1);

  const int rsw = lr & 7;
  for (int kt = 0; kt < nk; ++kt) {
    if (kt + 1 < nk) asm volatile("s_waitcnt vmcnt(4)" ::: "memory");
    else             asm volatile("s_waitcnt vmcnt(0)" ::: "memory");
    asm volatile("s_barrier" ::: "memory");
    const u16* base = lds[kt & 1];
    bf16x8_t bfr[2][2];
#pragma unroll
    for (int n = 0; n < 2; ++n)
#pragma unroll
      for (int ks = 0; ks < 2; ++ks)
        bfr[n][ks] = ld8(base + 8192 + (wn * 32 + n * 16 + lr) * 64 +
                         (((ks * 4 + lg) ^ rsw) * 8));
#pragma unroll
    for (int p = 0; p < 2; ++p) {
      bf16x8_t af[2][2];
#pragma unroll
      for (int mi = 0; mi < 2; ++mi)
#pragma unroll
        for (int ks = 0; ks < 2; ++ks)
          af[mi][ks] = ld8(base + (wm * 64 + (p * 2 + mi) * 16 + lr) * 64 +
                           (((ks * 4 + lg) ^ rsw) * 8));
      __builtin_amdgcn_s_setprio(1);
#pragma unroll
      for (int mi = 0; mi < 2; ++mi)
#pragma unroll
        for (int n = 0; n < 2; ++n) {
          acc[p * 2 + mi][n] = mfma16(af[mi][0], bfr[n][0], acc[p * 2 + mi][n]);
          acc[p * 2 + mi][n] = mfma16(af[mi][1], bfr[n][1], acc[p * 2 + mi][n]);
        }
      __builtin_amdgcn_s_setprio(0);
    }
    asm volatile("s_barrier" ::: "memory");
    if (kt + 2 < nk) stage(kt & 1, kt + 2);
  }

#pragma unroll
  for (int m = 0; m < 4; ++m)
#pragma unroll
    for (int n = 0; n < 2; ++n) {
      const int col = nb + wn * 32 + n * 16 + lr;
#pragma unroll
      for (int r = 0; r < 4; ++r) {
        const int row = mb + wm * 64 + m * 16 + lg * 4 + r;
        Cm[(size_t)row * N + col] = acc[m][n][r];
      }
    }
}

// ---------------- flash attention v11 (unchanged) ----------------
__global__ __launch_bounds__(256, 2)
void flash_kernel(const u16* __restrict__ q, const u16* __restrict__ k,
                  const u16* __restrict__ vt, u16* __restrict__ y) {
  __shared__ u16 kbuf[2][4096];
  __shared__ u16 vbuf[2][4096];
  __shared__ u16 plds[4][2048];   // per-wave 32x64
  const int tid = threadIdx.x;
  const int w = tid >> 6, lane = tid & 63, lr = lane & 15, lg = lane >> 4;
  const int bx = blockIdx.x;
  const int xb = 15 - (bx >> 6);          // heavy q-tiles first
  const int bh = bx & 63;
  const int b = bh >> 5, h = bh & 31, hkv = h >> 2;
  const u16* kb_base = k + ((size_t)(b * HKVn + hkv)) * Tn * Dn;
  const u16* vb_base = vt + ((size_t)(b * HKVn + hkv)) * Dn * Tn;

  const int qb0 = xb * 128;
  const int ntiles = 2 * xb + 2;          // >= 2 always
  const int qw0 = qb0 + w * 32;
  const int qrow0 = qw0 + lr;

  const int slot0 = w * 128 + lane;
  const int slot1 = slot0 + 64;
  const int r0 = slot0 >> 3, c0 = (slot0 & 7) ^ (r0 & 7);
  const int r1 = slot1 >> 3, c1 = (slot1 & 7) ^ (r1 & 7);
  const u16* ksrc0 = kb_base + r0 * Dn + c0 * 8;
  const u16* ksrc1 = kb_base + r1 * Dn + c1 * 8;
  const u16* vsrc0 = vb_base + r0 * Tn + c0 * 8;
  const u16* vsrc1 = vb_base + r1 * Tn + c1 * 8;

  int off[4][2];
#pragma unroll
  for (int i = 0; i < 4; ++i)
#pragma unroll
    for (int ks = 0; ks < 2; ++ks)
      off[i][ks] = (i * 16 + lr) * 64 + (((ks * 4 + lg) ^ (lr & 7)) * 8);

  u16* pw = plds[w];
  const int swz = (lr & 7) * 8;

  auto stageKV = [&](int buf, int t) {
    const int ko = t * 64 * Dn;
    const int vo_ = t * 64;
    async16(&kbuf[buf][slot0 * 8], ksrc0 + ko);
    async16(&kbuf[buf][slot1 * 8], ksrc1 + ko);
    async16(&vbuf[buf][slot0 * 8], vsrc0 + vo_);
    async16(&vbuf[buf][slot1 * 8], vsrc1 + vo_);
  };

  bf16x8_t aq[2][2];
  {
    const u16* qp = q + (((size_t)(b * Hn + h)) * Tn + qw0 + lr) * Dn + lg * 8;
    aq[0][0] = ld8(qp);
    aq[0][1] = ld8(qp + 32);
    aq[1][0] = ld8(qp + 16 * Dn);
    aq[1][1] = ld8(qp + 16 * Dn + 32);
  }

  f32x4 acc[2][4] = {};
  float lsum[2] = { 0.f, 0.f };   // per-lane partials until the epilogue
  const f32x4 cinit = { -FMAXC, -FMAXC, -FMAXC, -FMAXC };

  stageKV(0, 0);
  stageKV(1, 1);

  for (int kb = 0; kb < ntiles; ++kb) {
    if (kb + 1 < ntiles) asm volatile("s_waitcnt vmcnt(4)" ::: "memory");
    else                 asm volatile("s_waitcnt vmcnt(0)" ::: "memory");
    asm volatile("s_barrier" ::: "memory");
    const int kp0 = kb * 64;
    if (kp0 <= qw0 + 31) {
      const u16* kl = kbuf[kb & 1];
      const u16* vl = vbuf[kb & 1];
      f32x4 sc[2][4] = { { cinit, cinit, cinit, cinit },
                         { cinit, cinit, cinit, cinit } };
#pragma unroll
      for (int ks = 0; ks < 2; ++ks) {
        bf16x8_t kf0 = ld8(kl + off[0][ks]);
        bf16x8_t kf1 = ld8(kl + off[1][ks]);
        bf16x8_t kf2 = ld8(kl + off[2][ks]);
        bf16x8_t kf3 = ld8(kl + off[3][ks]);
#pragma unroll
        for (int rt = 0; rt < 2; ++rt) {
          sc[rt][0] = mfma16(kf0, aq[rt][ks], sc[rt][0]);
          sc[rt][1] = mfma16(kf1, aq[rt][ks], sc[rt][1]);
          sc[rt][2] = mfma16(kf2, aq[rt][ks], sc[rt][2]);
          sc[rt][3] = mfma16(kf3, aq[rt][ks], sc[rt][3]);
        }
      }
      // softmax + P write (both rt), fixed max; lsum stays per-lane
#pragma unroll
      for (int rt = 0; rt < 2; ++rt) {
        const int qrow = qrow0 + rt * 16;
        const bool needmask = (kp0 + 63) > (qw0 + rt * 16);
        if (needmask) {
#pragma unroll
          for (int kt = 0; kt < 4; ++kt) {
            const int kbase = kp0 + kt * 16 + lg * 4;
#pragma unroll
            for (int jj = 0; jj < 4; ++jj)
              if ((kbase + jj) > qrow) sc[rt][kt][jj] = -3e38f;
          }
        }
        float tsum[4];
#pragma unroll
        for (int kt = 0; kt < 4; ++kt) {
#pragma unroll
          for (int jj = 0; jj < 4; ++jj)
            sc[rt][kt][jj] = EXP2(sc[rt][kt][jj]);
          tsum[kt] = (sc[rt][kt][0] + sc[rt][kt][1]) +
                     (sc[rt][kt][2] + sc[rt][kt][3]);
        }
        lsum[rt] += (tsum[0] + tsum[1]) + (tsum[2] + tsum[3]);
#pragma unroll
        for (int kt = 0; kt < 4; ++kt) {
          u16x4 pk = { f2b(sc[rt][kt][0]), f2b(sc[rt][kt][1]),
                       f2b(sc[rt][kt][2]), f2b(sc[rt][kt][3]) };
          *reinterpret_cast<u16x4*>(
              pw + (rt * 16 + lr) * 64 + ((kt * 16 + lg * 4) ^ swz)) = pk;
        }
      }
      // PV once: each V fragment read a single time, feeds both rt
#pragma unroll
      for (int ks = 0; ks < 2; ++ks) {
        bf16x8_t pb0 = ld8(pw + lr * 64 + ((ks * 32 + lg * 8) ^ swz));
        bf16x8_t pb1 = ld8(pw + (16 + lr) * 64 + ((ks * 32 + lg * 8) ^ swz));
#pragma unroll
        for (int dt = 0; dt < 4; ++dt) {
          bf16x8_t vf = ld8(vl + off[dt][ks]);
          acc[0][dt] = mfma16(vf, pb0, acc[0][dt]);
          acc[1][dt] = mfma16(vf, pb1, acc[1][dt]);
        }
      }
    }
    asm volatile("s_barrier" ::: "memory");   // all waves done reading buf
    if (kb + 2 < ntiles) stageKV(kb & 1, kb + 2);
  }

  // deferred cross-lane-group lsum reduction (once)
#pragma unroll
  for (int rt = 0; rt < 2; ++rt) {
    lsum[rt] += __shfl_xor(lsum[rt], 16, 64);
    lsum[rt] += __shfl_xor(lsum[rt], 32, 64);
  }

  u16* scratch = &kbuf[0][0] + w * 2048;   // 32x64 per wave (loop drained)
#pragma unroll
  for (int rt = 0; rt < 2; ++rt) {
    float inv = 1.f / lsum[rt];
#pragma unroll
    for (int dt = 0; dt < 4; ++dt) {
      u16x4 pk = { f2b(acc[rt][dt][0] * inv), f2b(acc[rt][dt][1] * inv),
                   f2b(acc[rt][dt][2] * inv), f2b(acc[rt][dt][3] * inv) };
      *reinterpret_cast<u16x4*>(
          scratch + (rt * 16 + lr) * 64 + ((dt * 16 + lg * 4) ^ swz)) = pk;
    }
  }
#pragma unroll
  for (int it = 0; it < 4; ++it) {
    const int row = it * 8 + (lane >> 3);
    const int col = (lane & 7) * 8;
    s16x8 vv = *reinterpret_cast<const s16x8*>(
        scratch + row * 64 + (col ^ ((row & 7) * 8)));
    *reinterpret_cast<s16x8*>(
        y + ((size_t)b * Tn + qb0 + w * 32 + row) * Cn + h * 64 + col) = vv;
  }
}

// ---------------- launch ----------------
extern "C" void kernel_launch(void* const* d_in, const int* in_sizes, int n_in,
                              void* d_out, int out_size, void* d_ws, size_t ws_size,
                              hipStream_t stream) {
  const float* x  = (const float*)d_in[0];
  const float* wq = (const float*)d_in[2];
  const float* wk = (const float*)d_in[3];
  const float* wv = (const float*)d_in[4];
  const float* wc = (const float*)d_in[5];
  float* out = (float*)d_out;
  char* ws = (char*)d_ws;

  const size_t NX   = (size_t)Bn * Tn * Cn;        // 8388608
  const size_t NWQ  = (size_t)Cn * Cn;             // 4194304
  const size_t NWK  = (size_t)HKVn * Dn * Cn;      // 1048576
  const size_t NQ   = (size_t)Bn * Hn * Tn * Dn;   // 8388608
  const size_t NKV  = (size_t)Bn * HKVn * Tn * Dn; // 2097152

  size_t off = 0;
  u16* xb    = (u16*)(ws + off); off += NX * 2;               // reused as y after QKV gemm
  u16* wqkvb = (u16*)(ws + off); off += (NWQ + 2 * NWK) * 2;
  u16* wcb   = (u16*)(ws + off); off += NWQ * 2;
  u16* qr    = (u16*)(ws + off); off += NQ * 2;
  u16* kr    = (u16*)(ws + off); off += NKV * 2;
  u16* vt    = (u16*)(ws + off); off += NKV * 2;
  float* cs  = (float*)(ws + off); off += (size_t)Tn * 32 * 4;
  float* sn  = (float*)(ws + off); off += (size_t)Tn * 32 * 4;

  u16* y = xb;   // xb dead after QKV GEMM; flash writes y here

  cast_all<<<2048, 256, 0, stream>>>(x, wq, wk, wv, wc, xb, wqkvb, wcb, cs, sn);

  gemm_qkv_rope256<<<dim3(32, 24), 512, 0, stream>>>(
      xb, wqkvb, cs, sn, qr, kr, vt, Cn);

  flash_kernel<<<dim3(1024), 256, 0, stream>>>(qr, kr, vt, y);

  gemm_proj256<<<dim3(32, 16), 512, 0, stream>>>(
      y, wcb, out, Cn, Cn);

  (void)in_sizes; (void)n_in; (void)out_size; (void)ws_size;
}

// Round 25
// 153.570 us; speedup vs baseline: 1.0910x; 1.0910x over previous
//
#include <hip/hip_runtime.h>
#include <hip/hip_bf16.h>
#include <math.h>

typedef unsigned short u16;
typedef short s16x8 __attribute__((ext_vector_type(8)));
typedef u16 u16x4 __attribute__((ext_vector_type(4)));
typedef __bf16 bf16x8_t __attribute__((ext_vector_type(8)));
typedef float f32x4 __attribute__((ext_vector_type(4)));

#define DEVI static __device__ __forceinline__

static constexpr int Bn = 2, Tn = 2048, Cn = 2048, Hn = 32, HKVn = 8, Dn = 64;
static constexpr int NCOL = Cn + 2 * HKVn * Dn;   // 3072
// Q pre-scale: 1/sqrt(64) * log2(e) -> scores already in exp2 domain
#define QSCALE 0.18033688011f
// Fixed softmax max (exp2 domain): scores ~N(0,1.44), max over 4M ~ +-8;
// M=24 is ~16 sigma; p = exp2(s-24) keeps full relative precision.
#define FMAXC 24.0f

#if __has_builtin(__builtin_amdgcn_exp2f)
#define EXP2(x) __builtin_amdgcn_exp2f(x)
#else
#define EXP2(x) exp2f(x)
#endif

DEVI u16 f2b(float f) {
  __hip_bfloat16 h = __float2bfloat16(f);
  return __builtin_bit_cast(u16, h);
}
DEVI float b2f(u16 u) {
  __hip_bfloat16 h = __builtin_bit_cast(__hip_bfloat16, u);
  return __bfloat162float(h);
}
DEVI bf16x8_t ld8(const u16* p) {
  s16x8 v = *reinterpret_cast<const s16x8*>(p);
  return __builtin_bit_cast(bf16x8_t, v);
}
DEVI f32x4 mfma16(bf16x8_t a, bf16x8_t b, f32x4 c) {
  return __builtin_amdgcn_mfma_f32_16x16x32_bf16(a, b, c, 0, 0, 0);
}
DEVI void async16(u16* lds_dst, const u16* gsrc) {
  __builtin_amdgcn_global_load_lds(
      (__attribute__((address_space(1))) void*)(gsrc),
      (__attribute__((address_space(3))) void*)(lds_dst), 16, 0, 0);
}

// ---------------- fused input casts + rope table (1 launch) ----------------
__global__ void cast_all(const float* __restrict__ x, const float* __restrict__ wq,
                         const float* __restrict__ wk, const float* __restrict__ wv,
                         const float* __restrict__ wc, u16* __restrict__ xb,
                         u16* __restrict__ wqkvb, u16* __restrict__ wcb,
                         float* __restrict__ cs, float* __restrict__ sn) {
  constexpr int NX4 = 2097152, NWQ4 = 1048576, NWK4 = 262144;
  constexpr int TOT = NX4 + NWQ4 + 2 * NWK4 + NWQ4;   // 4718592
  const int stride = gridDim.x * blockDim.x;
  const int tid0 = blockIdx.x * blockDim.x + threadIdx.x;
  for (int i = tid0; i < TOT; i += stride) {
    const float4* sv;
    u16x4* dv;
    if (i < NX4) {
      sv = (const float4*)x + i; dv = (u16x4*)xb + i;
    } else if (i < NX4 + NWQ4) {
      const int j = i - NX4;
      sv = (const float4*)wq + j; dv = (u16x4*)wqkvb + j;
    } else if (i < NX4 + NWQ4 + NWK4) {
      const int j = i - NX4 - NWQ4;
      sv = (const float4*)wk + j; dv = (u16x4*)wqkvb + NWQ4 + j;
    } else if (i < NX4 + NWQ4 + 2 * NWK4) {
      const int j = i - NX4 - NWQ4 - NWK4;
      sv = (const float4*)wv + j; dv = (u16x4*)wqkvb + NWQ4 + NWK4 + j;
    } else {
      const int j = i - NX4 - NWQ4 - 2 * NWK4;
      sv = (const float4*)wc + j; dv = (u16x4*)wcb + j;
    }
    const float4 v = *sv;
    u16x4 o = { f2b(v.x), f2b(v.y), f2b(v.z), f2b(v.w) };
    *dv = o;
  }
  // rope table: 2048 x 32 entries
  if (tid0 < Tn * 32) {
    const int t = tid0 >> 5, d2 = tid0 & 31;
    const float inv = powf(10000.0f, -(float)d2 / 32.0f);
    const float fr = (float)t * inv;
    cs[tid0] = cosf(fr);
    sn[tid0] = sinf(fr);
  }
}

// ======== QKV GEMM, 128x192 tile, BK=64, 8 waves, counted-vmcnt pipeline =====
// R23 config (measured 56.8us, MfmaUtil 40%, 2 blocks/CU at 80KB LDS).
// R24's BK=32 / 4-block attempt REGRESSED (76.6us: occupancy stayed 16
// waves/CU while barriers doubled) -- reverted.
__global__ __launch_bounds__(512, 2)
void gemm_qkv_rope256(const u16* __restrict__ A, const u16* __restrict__ Bm,
                      const float* __restrict__ cs, const float* __restrict__ sn,
                      u16* __restrict__ qo, u16* __restrict__ ko,
                      u16* __restrict__ vo, int K) {
  __shared__ u16 lds[2][20480];   // 80 KB total
  const int tid = threadIdx.x;
  const int mb = blockIdx.x * 128, nb = blockIdx.y * 192;
  const int lane = tid & 63, lr = lane & 15, lg = lane >> 4;
  const int w = tid >> 6, wm = w >> 2, wn = w & 3;
  const int nk = K >> 6;   // BK = 64

  auto stage = [&](int buf, int kt) {
#pragma unroll
    for (int h = 0; h < 5; ++h) {
      if (h < 2) {
        const int s = h * 512 + tid;          // A slots 0..1023
        const int row = s >> 3;               // 0..127
        const int c = (s & 7) ^ (row & 7);
        async16(&lds[buf][s * 8], A + (size_t)(mb + row) * K + kt * 64 + c * 8);
      } else {
        const int s = (h - 2) * 512 + tid;    // B slots 0..1535
        const int row = s >> 3;               // 0..191
        const int c = (s & 7) ^ (row & 7);
        async16(&lds[buf][8192 + s * 8],
                Bm + (size_t)(nb + row) * K + kt * 64 + c * 8);
      }
    }
  };

  f32x4 acc[4][3] = {};
  stage(0, 0);
  stage(1, 1);

  const int rsw = lr & 7;
  for (int kt = 0; kt < nk; ++kt) {
    if (kt + 1 < nk) asm volatile("s_waitcnt vmcnt(5)" ::: "memory");
    else             asm volatile("s_waitcnt vmcnt(0)" ::: "memory");
    asm volatile("s_barrier" ::: "memory");
    const u16* base = lds[kt & 1];
    bf16x8_t bfr[3][2];
#pragma unroll
    for (int n = 0; n < 3; ++n)
#pragma unroll
      for (int ks = 0; ks < 2; ++ks)
        bfr[n][ks] = ld8(base + 8192 + (wn * 48 + n * 16 + lr) * 64 +
                         (((ks * 4 + lg) ^ rsw) * 8));
#pragma unroll
    for (int p = 0; p < 2; ++p) {
      bf16x8_t af[2][2];
#pragma unroll
      for (int mi = 0; mi < 2; ++mi)
#pragma unroll
        for (int ks = 0; ks < 2; ++ks)
          af[mi][ks] = ld8(base + (wm * 64 + (p * 2 + mi) * 16 + lr) * 64 +
                           (((ks * 4 + lg) ^ rsw) * 8));
      __builtin_amdgcn_s_setprio(1);
#pragma unroll
      for (int mi = 0; mi < 2; ++mi)
#pragma unroll
        for (int n = 0; n < 3; ++n) {
          acc[p * 2 + mi][n] = mfma16(af[mi][0], bfr[n][0], acc[p * 2 + mi][n]);
          acc[p * 2 + mi][n] = mfma16(af[mi][1], bfr[n][1], acc[p * 2 + mi][n]);
        }
      __builtin_amdgcn_s_setprio(0);
    }
    asm volatile("s_barrier" ::: "memory");   // all waves done reading buf
    if (kt + 2 < nk) stage(kt & 1, kt + 2);
  }
  __syncthreads();

  // ---- per-frag: V region direct store; Q/K into LDS tile (128x192) ----
  u16* tile = &lds[0][0];     // 24576 u16 = 48KB
#pragma unroll
  for (int m = 0; m < 4; ++m)
#pragma unroll
    for (int n = 0; n < 3; ++n) {
      const int fragcol = nb + wn * 48 + n * 16;   // 16-aligned, uniform
      if (fragcol >= Cn + 512) {
        const int cc = fragcol + lr - Cn - 512;
        const int d = cc & 63, h = cc >> 6;
        const int row0 = mb + wm * 64 + m * 16 + lg * 4;
        const int b = row0 >> 11, t0 = row0 & 2047;
        u16x4 pk = { f2b(acc[m][n][0]), f2b(acc[m][n][1]),
                     f2b(acc[m][n][2]), f2b(acc[m][n][3]) };
        *reinterpret_cast<u16x4*>(
            vo + (((size_t)b * HKVn + h) * Dn + d) * Tn + t0) = pk;
      } else {
        const int colc = wn * 48 + n * 16 + lr;    // 0..191
#pragma unroll
        for (int r = 0; r < 4; ++r) {
          const int row = wm * 64 + m * 16 + lg * 4 + r;   // 0..127
          tile[row * 192 + (((colc >> 3) ^ (row & 7)) << 3) + (colc & 7)] =
              f2b(acc[m][n][r]);
        }
      }
    }
  if (nb >= Cn + 512) return;    // pure-V tile (uniform)
  __syncthreads();

  // ---- RoPE re-read: 128 rows x 24 chunks = 3072 units ----
#pragma unroll
  for (int it = 0; it < 6; ++it) {
    const int unit = it * 512 + tid;
    const int tl = unit / 24;              // tile row 0..127
    const int ch = unit - tl * 24;         // chunk 0..23
    const int gcol = nb + ch * 8;
    if (gcol >= Cn + 512) continue;        // V cols in mixed tile: skip
    const int c = ch & 7;                  // chunk within 64-col head
    const int sw = tl & 7;
    const s16x8 v0 = *reinterpret_cast<const s16x8*>(
        tile + tl * 192 + ((ch ^ sw) << 3));
    const s16x8 v1 = *reinterpret_cast<const s16x8*>(
        tile + tl * 192 + (((ch ^ 4) ^ sw) << 3));
    const int grow = mb + tl, b = grow >> 11, t = grow & 2047;
    const float4 c0 = *reinterpret_cast<const float4*>(cs + t * 32 + (c & 3) * 8);
    const float4 c1 = *reinterpret_cast<const float4*>(cs + t * 32 + (c & 3) * 8 + 4);
    const float4 s0 = *reinterpret_cast<const float4*>(sn + t * 32 + (c & 3) * 8);
    const float4 s1 = *reinterpret_cast<const float4*>(sn + t * 32 + (c & 3) * 8 + 4);
    const float cf[8] = { c0.x, c0.y, c0.z, c0.w, c1.x, c1.y, c1.z, c1.w };
    const float sf[8] = { s0.x, s0.y, s0.z, s0.w, s1.x, s1.y, s1.z, s1.w };
    const float sgn = (c < 4) ? -1.f : 1.f;
    const bool isQ = (gcol < Cn);
    const float scale = isQ ? QSCALE : 1.f;
    u16 outv[8];
#pragma unroll
    for (int e = 0; e < 8; ++e) {
      const float a0 = b2f((u16)v0[e]);
      const float a1 = b2f((u16)v1[e]);
      outv[e] = f2b((a0 * cf[e] + sgn * a1 * sf[e]) * scale);
    }
    u16* dst;
    if (isQ) {
      const int h = gcol >> 6;
      dst = qo + (((size_t)b * Hn + h) * Tn + t) * Dn + c * 8;
    } else {
      const int h = (gcol - Cn) >> 6;
      dst = ko + (((size_t)b * HKVn + h) * Tn + t) * Dn + c * 8;
    }
    *reinterpret_cast<s16x8*>(dst) = *reinterpret_cast<const s16x8*>(outv);
  }
}

// ======== proj GEMM, 128x128 tile, BK=64, 8 waves, counted-vmcnt pipeline ====
__global__ __launch_bounds__(512, 2)
void gemm_proj256(const u16* __restrict__ A, const u16* __restrict__ Bm,
                  float* __restrict__ Cm, int N, int K) {
  __shared__ u16 lds[2][16384];   // 64 KB
  const int tid = threadIdx.x;
  const int mb = blockIdx.x * 128, nb = blockIdx.y * 128;
  const int lane = tid & 63, lr = lane & 15, lg = lane >> 4;
  const int w = tid >> 6, wm = w >> 2, wn = w & 3;
  const int nk = K >> 6;   // BK = 64

  auto stage = [&](int buf, int kt) {
#pragma unroll
    for (int h = 0; h < 4; ++h) {
      if (h < 2) {
        const int s = h * 512 + tid;          // A slots 0..1023
        const int row = s >> 3;               // 0..127
        const int c = (s & 7) ^ (row & 7);
        async16(&lds[buf][s * 8], A + (size_t)(mb + row) * K + kt * 64 + c * 8);
      } else {
        const int s = (h - 2) * 512 + tid;    // B slots 0..1023
        const int row = s >> 3;               // 0..127
        const int c = (s & 7) ^ (row & 7);
        async16(&lds[buf][8192 + s * 8],
                Bm + (size_t)(nb + row) * K + kt * 64 + c * 8);
      }
    }
  };

  f32x4 acc[4][2] = {};
  stage(0, 0);
  stage(1, 1);

  const int rsw = lr & 7;
  for (int kt = 0; kt < nk; ++kt) {
    if (kt + 1 < nk) asm volatile("s_waitcnt vmcnt(4)" ::: "memory");
    else             asm volatile("s_waitcnt vmcnt(0)" ::: "memory");
    asm volatile("s_barrier" ::: "memory");
    const u16* base = lds[kt & 1];
    bf16x8_t bfr[2][2];
#pragma unroll
    for (int n = 0; n < 2; ++n)
#pragma unroll
      for (int ks = 0; ks < 2; ++ks)
        bfr[n][ks] = ld8(base + 8192 + (wn * 32 + n * 16 + lr) * 64 +
                         (((ks * 4 + lg) ^ rsw) * 8));
#pragma unroll
    for (int p = 0; p < 2; ++p) {
      bf16x8_t af[2][2];
#pragma unroll
      for (int mi = 0; mi < 2; ++mi)
#pragma unroll
        for (int ks = 0; ks < 2; ++ks)
          af[mi][ks] = ld8(base + (wm * 64 + (p * 2 + mi) * 16 + lr) * 64 +
                           (((ks * 4 + lg) ^ rsw) * 8));
      __builtin_amdgcn_s_setprio(1);
#pragma unroll
      for (int mi = 0; mi < 2; ++mi)
#pragma unroll
        for (int n = 0; n < 2; ++n) {
          acc[p * 2 + mi][n] = mfma16(af[mi][0], bfr[n][0], acc[p * 2 + mi][n]);
          acc[p * 2 + mi][n] = mfma16(af[mi][1], bfr[n][1], acc[p * 2 + mi][n]);
        }
      __builtin_amdgcn_s_setprio(0);
    }
    asm volatile("s_barrier" ::: "memory");
    if (kt + 2 < nk) stage(kt & 1, kt + 2);
  }

#pragma unroll
  for (int m = 0; m < 4; ++m)
#pragma unroll
    for (int n = 0; n < 2; ++n) {
      const int col = nb + wn * 32 + n * 16 + lr;
#pragma unroll
      for (int r = 0; r < 4; ++r) {
        const int row = mb + wm * 64 + m * 16 + lg * 4 + r;
        Cm[(size_t)row * N + col] = acc[m][n][r];
      }
    }
}

// ---------------- flash attention v11 (unchanged) ----------------
__global__ __launch_bounds__(256, 2)
void flash_kernel(const u16* __restrict__ q, const u16* __restrict__ k,
                  const u16* __restrict__ vt, u16* __restrict__ y) {
  __shared__ u16 kbuf[2][4096];
  __shared__ u16 vbuf[2][4096];
  __shared__ u16 plds[4][2048];   // per-wave 32x64
  const int tid = threadIdx.x;
  const int w = tid >> 6, lane = tid & 63, lr = lane & 15, lg = lane >> 4;
  const int bx = blockIdx.x;
  const int xb = 15 - (bx >> 6);          // heavy q-tiles first
  const int bh = bx & 63;
  const int b = bh >> 5, h = bh & 31, hkv = h >> 2;
  const u16* kb_base = k + ((size_t)(b * HKVn + hkv)) * Tn * Dn;
  const u16* vb_base = vt + ((size_t)(b * HKVn + hkv)) * Dn * Tn;

  const int qb0 = xb * 128;
  const int ntiles = 2 * xb + 2;          // >= 2 always
  const int qw0 = qb0 + w * 32;
  const int qrow0 = qw0 + lr;

  const int slot0 = w * 128 + lane;
  const int slot1 = slot0 + 64;
  const int r0 = slot0 >> 3, c0 = (slot0 & 7) ^ (r0 & 7);
  const int r1 = slot1 >> 3, c1 = (slot1 & 7) ^ (r1 & 7);
  const u16* ksrc0 = kb_base + r0 * Dn + c0 * 8;
  const u16* ksrc1 = kb_base + r1 * Dn + c1 * 8;
  const u16* vsrc0 = vb_base + r0 * Tn + c0 * 8;
  const u16* vsrc1 = vb_base + r1 * Tn + c1 * 8;

  int off[4][2];
#pragma unroll
  for (int i = 0; i < 4; ++i)
#pragma unroll
    for (int ks = 0; ks < 2; ++ks)
      off[i][ks] = (i * 16 + lr) * 64 + (((ks * 4 + lg) ^ (lr & 7)) * 8);

  u16* pw = plds[w];
  const int swz = (lr & 7) * 8;

  auto stageKV = [&](int buf, int t) {
    const int ko = t * 64 * Dn;
    const int vo_ = t * 64;
    async16(&kbuf[buf][slot0 * 8], ksrc0 + ko);
    async16(&kbuf[buf][slot1 * 8], ksrc1 + ko);
    async16(&vbuf[buf][slot0 * 8], vsrc0 + vo_);
    async16(&vbuf[buf][slot1 * 8], vsrc1 + vo_);
  };

  bf16x8_t aq[2][2];
  {
    const u16* qp = q + (((size_t)(b * Hn + h)) * Tn + qw0 + lr) * Dn + lg * 8;
    aq[0][0] = ld8(qp);
    aq[0][1] = ld8(qp + 32);
    aq[1][0] = ld8(qp + 16 * Dn);
    aq[1][1] = ld8(qp + 16 * Dn + 32);
  }

  f32x4 acc[2][4] = {};
  float lsum[2] = { 0.f, 0.f };   // per-lane partials until the epilogue
  const f32x4 cinit = { -FMAXC, -FMAXC, -FMAXC, -FMAXC };

  stageKV(0, 0);
  stageKV(1, 1);

  for (int kb = 0; kb < ntiles; ++kb) {
    if (kb + 1 < ntiles) asm volatile("s_waitcnt vmcnt(4)" ::: "memory");
    else                 asm volatile("s_waitcnt vmcnt(0)" ::: "memory");
    asm volatile("s_barrier" ::: "memory");
    const int kp0 = kb * 64;
    if (kp0 <= qw0 + 31) {
      const u16* kl = kbuf[kb & 1];
      const u16* vl = vbuf[kb & 1];
      f32x4 sc[2][4] = { { cinit, cinit, cinit, cinit },
                         { cinit, cinit, cinit, cinit } };
#pragma unroll
      for (int ks = 0; ks < 2; ++ks) {
        bf16x8_t kf0 = ld8(kl + off[0][ks]);
        bf16x8_t kf1 = ld8(kl + off[1][ks]);
        bf16x8_t kf2 = ld8(kl + off[2][ks]);
        bf16x8_t kf3 = ld8(kl + off[3][ks]);
#pragma unroll
        for (int rt = 0; rt < 2; ++rt) {
          sc[rt][0] = mfma16(kf0, aq[rt][ks], sc[rt][0]);
          sc[rt][1] = mfma16(kf1, aq[rt][ks], sc[rt][1]);
          sc[rt][2] = mfma16(kf2, aq[rt][ks], sc[rt][2]);
          sc[rt][3] = mfma16(kf3, aq[rt][ks], sc[rt][3]);
        }
      }
      // softmax + P write (both rt), fixed max; lsum stays per-lane
#pragma unroll
      for (int rt = 0; rt < 2; ++rt) {
        const int qrow = qrow0 + rt * 16;
        const bool needmask = (kp0 + 63) > (qw0 + rt * 16);
        if (needmask) {
#pragma unroll
          for (int kt = 0; kt < 4; ++kt) {
            const int kbase = kp0 + kt * 16 + lg * 4;
#pragma unroll
            for (int jj = 0; jj < 4; ++jj)
              if ((kbase + jj) > qrow) sc[rt][kt][jj] = -3e38f;
          }
        }
        float tsum[4];
#pragma unroll
        for (int kt = 0; kt < 4; ++kt) {
#pragma unroll
          for (int jj = 0; jj < 4; ++jj)
            sc[rt][kt][jj] = EXP2(sc[rt][kt][jj]);
          tsum[kt] = (sc[rt][kt][0] + sc[rt][kt][1]) +
                     (sc[rt][kt][2] + sc[rt][kt][3]);
        }
        lsum[rt] += (tsum[0] + tsum[1]) + (tsum[2] + tsum[3]);
#pragma unroll
        for (int kt = 0; kt < 4; ++kt) {
          u16x4 pk = { f2b(sc[rt][kt][0]), f2b(sc[rt][kt][1]),
                       f2b(sc[rt][kt][2]), f2b(sc[rt][kt][3]) };
          *reinterpret_cast<u16x4*>(
              pw + (rt * 16 + lr) * 64 + ((kt * 16 + lg * 4) ^ swz)) = pk;
        }
      }
      // PV once: each V fragment read a single time, feeds both rt
#pragma unroll
      for (int ks = 0; ks < 2; ++ks) {
        bf16x8_t pb0 = ld8(pw + lr * 64 + ((ks * 32 + lg * 8) ^ swz));
        bf16x8_t pb1 = ld8(pw + (16 + lr) * 64 + ((ks * 32 + lg * 8) ^ swz));
#pragma unroll
        for (int dt = 0; dt < 4; ++dt) {
          bf16x8_t vf = ld8(vl + off[dt][ks]);
          acc[0][dt] = mfma16(vf, pb0, acc[0][dt]);
          acc[1][dt] = mfma16(vf, pb1, acc[1][dt]);
        }
      }
    }
    asm volatile("s_barrier" ::: "memory");   // all waves done reading buf
    if (kb + 2 < ntiles) stageKV(kb & 1, kb + 2);
  }

  // deferred cross-lane-group lsum reduction (once)
#pragma unroll
  for (int rt = 0; rt < 2; ++rt) {
    lsum[rt] += __shfl_xor(lsum[rt], 16, 64);
    lsum[rt] += __shfl_xor(lsum[rt], 32, 64);
  }

  u16* scratch = &kbuf[0][0] + w * 2048;   // 32x64 per wave (loop drained)
#pragma unroll
  for (int rt = 0; rt < 2; ++rt) {
    float inv = 1.f / lsum[rt];
#pragma unroll
    for (int dt = 0; dt < 4; ++dt) {
      u16x4 pk = { f2b(acc[rt][dt][0] * inv), f2b(acc[rt][dt][1] * inv),
                   f2b(acc[rt][dt][2] * inv), f2b(acc[rt][dt][3] * inv) };
      *reinterpret_cast<u16x4*>(
          scratch + (rt * 16 + lr) * 64 + ((dt * 16 + lg * 4) ^ swz)) = pk;
    }
  }
#pragma unroll
  for (int it = 0; it < 4; ++it) {
    const int row = it * 8 + (lane >> 3);
    const int col = (lane & 7) * 8;
    s16x8 vv = *reinterpret_cast<const s16x8*>(
        scratch + row * 64 + (col ^ ((row & 7) * 8)));
    *reinterpret_cast<s16x8*>(
        y + ((size_t)b * Tn + qb0 + w * 32 + row) * Cn + h * 64 + col) = vv;
  }
}

// ---------------- launch ----------------
extern "C" void kernel_launch(void* const* d_in, const int* in_sizes, int n_in,
                              void* d_out, int out_size, void* d_ws, size_t ws_size,
                              hipStream_t stream) {
  const float* x  = (const float*)d_in[0];
  const float* wq = (const float*)d_in[2];
  const float* wk = (const float*)d_in[3];
  const float* wv = (const float*)d_in[4];
  const float* wc = (const float*)d_in[5];
  float* out = (float*)d_out;
  char* ws = (char*)d_ws;

  const size_t NX   = (size_t)Bn * Tn * Cn;        // 8388608
  const size_t NWQ  = (size_t)Cn * Cn;             // 4194304
  const size_t NWK  = (size_t)HKVn * Dn * Cn;      // 1048576
  const size_t NQ   = (size_t)Bn * Hn * Tn * Dn;   // 8388608
  const size_t NKV  = (size_t)Bn * HKVn * Tn * Dn; // 2097152

  size_t off = 0;
  u16* xb    = (u16*)(ws + off); off += NX * 2;               // reused as y after QKV gemm
  u16* wqkvb = (u16*)(ws + off); off += (NWQ + 2 * NWK) * 2;
  u16* wcb   = (u16*)(ws + off); off += NWQ * 2;
  u16* qr    = (u16*)(ws + off); off += NQ * 2;
  u16* kr    = (u16*)(ws + off); off += NKV * 2;
  u16* vt    = (u16*)(ws + off); off += NKV * 2;
  float* cs  = (float*)(ws + off); off += (size_t)Tn * 32 * 4;
  float* sn  = (float*)(ws + off); off += (size_t)Tn * 32 * 4;

  u16* y = xb;   // xb dead after QKV GEMM; flash writes y here

  cast_all<<<2048, 256, 0, stream>>>(x, wq, wk, wv, wc, xb, wqkvb, wcb, cs, sn);

  gemm_qkv_rope256<<<dim3(32, 16), 512, 0, stream>>>(
      xb, wqkvb, cs, sn, qr, kr, vt, Cn);

  flash_kernel<<<dim3(1024), 256, 0, stream>>>(qr, kr, vt, y);

  gemm_proj256<<<dim3(32, 16), 512, 0, stream>>>(
      y, wcb, out, Cn, Cn);

  (void)in_sizes; (void)n_in; (void)out_size; (void)ws_size;
}